// Round 19
// baseline (180.693 us; speedup 1.0000x reference)
//
#include <hip/hip_runtime.h>
#include <hip/hip_bf16.h>
#include <cstdint>

#define Bc    32
#define Sc    600
#define NHc   16
#define SP    640            // padded seq rows (alloc)
#define NKT   19             // 19 key tiles of 32 = 608
#define DHc   48
#define DP    64             // K/V row width
#define QW    48             // Q row width
#define SCALEc 0.14433756729740643f   // 48^-0.5 (folded into W12f/biasr for pr=0)

typedef __bf16    bf16x8 __attribute__((ext_vector_type(8)));
typedef float     f32x4  __attribute__((ext_vector_type(4)));
typedef float     f32x16 __attribute__((ext_vector_type(16)));
typedef uint32_t  u32x4  __attribute__((ext_vector_type(4)));
typedef _Float16  f16x2  __attribute__((ext_vector_type(2)));

static __device__ __forceinline__ f32x4 mfma16(bf16x8 a, bf16x8 b, f32x4 c) {
    return __builtin_amdgcn_mfma_f32_16x16x32_bf16(a, b, c, 0, 0, 0);
}
static __device__ __forceinline__ f32x16 mfma32(bf16x8 a, bf16x8 b, f32x16 c) {
    return __builtin_amdgcn_mfma_f32_32x32x16_bf16(a, b, c, 0, 0, 0);
}
static __device__ __forceinline__ float fdot2u(uint32_t a, uint32_t b, float c) {
    return __builtin_amdgcn_fdot2(__builtin_bit_cast(f16x2, a),
                                  __builtin_bit_cast(f16x2, b), c, false);
}
static __device__ __forceinline__ f32x16 fzero16() {
    f32x16 z;
    #pragma unroll
    for (int i = 0; i < 16; ++i) z[i] = 0.f;
    return z;
}
static __device__ __forceinline__ void gload_lds16(const void* g, void* l) {
    __builtin_amdgcn_global_load_lds(
        (const __attribute__((address_space(1))) unsigned int*)g,
        (__attribute__((address_space(3))) unsigned int*)l, 16, 0, 0);
}
static __device__ __forceinline__ void lds_fence() {
    asm volatile("s_waitcnt lgkmcnt(0)" ::: "memory");
}
static __device__ __forceinline__ uint32_t pkbf(float a, float b) {
    uint32_t r;
    asm("v_cvt_pk_bf16_f32 %0, %1, %2" : "=v"(r) : "v"(a), "v"(b));
    return r;
}

// ---------------------------------------------------------------------------
// Prep kernel (unchanged): input-independent weight tables.
// ---------------------------------------------------------------------------
__global__ __launch_bounds__(256) void prep(
    const float* __restrict__ wq1, const float* __restrict__ wq2,
    const float* __restrict__ wq3, const float* __restrict__ bq,
    const float* __restrict__ wk1, const float* __restrict__ wk2,
    const float* __restrict__ wk3, const float* __restrict__ bk,
    const float* __restrict__ wv1, const float* __restrict__ wv2,
    const float* __restrict__ wv3, const float* __restrict__ bv,
    __hip_bfloat16* __restrict__ W12f, float* __restrict__ biasr,
    uint32_t* __restrict__ w3f)
{
    const int pr = blockIdx.x, t = threadIdx.x;
    const float* w1 = pr == 0 ? wq1 : pr == 1 ? wk1 : wv1;
    const float* w2 = pr == 0 ? wq2 : pr == 1 ? wk2 : wv2;
    const float* w3 = pr == 0 ? wq3 : pr == 1 ? wk3 : wv3;
    const float* bb = pr == 0 ? bq  : pr == 1 ? bk  : bv;
    const float sc = pr == 0 ? SCALEc : 1.f;

    for (int grp = t; grp < 512; grp += 256) {
        int mkh = grp >> 6, lane = grp & 63;
        int m = mkh >> 1, kh = mkh & 1;
        int g = lane >> 4, r16 = lane & 15;
        float w1v = sc * w1[(2*m + (r16 >> 3))*8 + kh*4 + g];
        uint32_t wd[4];
        #pragma unroll
        for (int q = 0; q < 4; ++q)
            wd[q] = pkbf(w1v * w2[(r16 & 7)*8 + 2*q], w1v * w2[(r16 & 7)*8 + 2*q + 1]);
        *(uint4*)((unsigned short*)W12f + ((size_t)pr*512 + grp)*8)
            = make_uint4(wd[0], wd[1], wd[2], wd[3]);
    }
    for (int idx = t; idx < 768; idx += 256) {
        int h = idx / 48, dh = idx - h*48;
        int xq = dh / 12, r2 = dh - xq*12, yq = r2 / 3, z = r2 - yq*3;
        int a = xq*2 + (h >> 3), c = yq*2 + ((h >> 2) & 1), d = z*4 + (h & 3);
        biasr[(size_t)pr*768 + idx] = sc * bb[a*96 + c*12 + d];
    }
    if (t < 72) {
        int d = t / 6, q = t - d*6;
        w3f[((size_t)pr*12 + d)*8 + q] = __builtin_bit_cast(uint32_t,
            __builtin_amdgcn_cvt_pkrtz(w3[d*12 + 2*q], w3[d*12 + 2*q + 1]));
    }
}

// ---------------------------------------------------------------------------
// Fused Q/K/V TLE (R16 1-wave form, unchanged). grid = 4800, block = 64
// ---------------------------------------------------------------------------
__global__ __launch_bounds__(64, 4) void tle_qkv(
    const float* __restrict__ x,
    const __hip_bfloat16* __restrict__ W12f, const float* __restrict__ biasr,
    const uint32_t* __restrict__ w3f,
    __hip_bfloat16* __restrict__ Qb, __hip_bfloat16* __restrict__ Kb,
    __hip_bfloat16* __restrict__ Vr)
{
    __shared__ __align__(16) char uni[4*864*2];           // 6912 B
    unsigned short* xb  = (unsigned short*)uni;
    unsigned short* t2s = (unsigned short*)uni;
    const int t = threadIdx.x;
    const int patch0 = blockIdx.x * 4;

    {   // phase 1: x -> xb transposed bf16
        const int pl = t >> 4, ij0 = (t & 15) * 4;
        const float4* xg = (const float4*)(x + (size_t)(patch0 + pl) * 768 + ij0*12);
        float vv[4][12];
        #pragma unroll
        for (int ij = 0; ij < 4; ++ij) {
            float4 a = xg[ij*3+0], b = xg[ij*3+1], c = xg[ij*3+2];
            vv[ij][0]=a.x; vv[ij][1]=a.y; vv[ij][2]=a.z;  vv[ij][3]=a.w;
            vv[ij][4]=b.x; vv[ij][5]=b.y; vv[ij][6]=b.z;  vv[ij][7]=b.w;
            vv[ij][8]=c.x; vv[ij][9]=c.y; vv[ij][10]=c.z; vv[ij][11]=c.w;
        }
        #pragma unroll
        for (int k = 0; k < 12; ++k) {
            uint32_t lo = pkbf(vv[0][k], vv[1][k]);
            uint32_t hi = pkbf(vv[2][k], vv[3][k]);
            *(uint2*)&xb[pl*864 + k*72 + ij0] = make_uint2(lo, hi);
        }
    }
    lds_fence();

    const int l = t;
    const int r16 = l & 15, g = l >> 4;

    bf16x8 Bf[3][2];
    int pl_c[3], k_c[3];
    #pragma unroll
    for (int n = 0; n < 3; ++n) {
        int col = n*16 + r16;
        int pp = col / 12, kk = col - pp*12;
        pl_c[n] = pp; k_c[n] = kk;
        #pragma unroll
        for (int kh = 0; kh < 2; ++kh)
            Bf[n][kh] = *(const bf16x8*)&xb[pp*864 + kk*72 + kh*32 + g*8];
    }
    lds_fence();

    const int plo = t >> 4, h = t & 15;
    const int h3 = h & 3;
    const int patch3 = patch0 + plo;
    const int b3 = patch3 / Sc, s3 = patch3 - b3*Sc;
    const bf16x8* W12p = (const bf16x8*)W12f;

    #pragma unroll 1
    for (int pr = 0; pr < 3; ++pr) {
        bf16x8 Af[4][2];
        #pragma unroll
        for (int m = 0; m < 4; ++m)
            #pragma unroll
            for (int kh = 0; kh < 2; ++kh)
                Af[m][kh] = W12p[((size_t)pr*8 + m*2 + kh)*64 + l];
        f32x4 acc[4][3];
        #pragma unroll
        for (int m = 0; m < 4; ++m)
            #pragma unroll
            for (int n = 0; n < 3; ++n) acc[m][n] = f32x4{0.f,0.f,0.f,0.f};
        #pragma unroll
        for (int m = 0; m < 4; ++m)
            #pragma unroll
            for (int n = 0; n < 3; ++n) {
                acc[m][n] = mfma16(Af[m][0], Bf[n][0], acc[m][n]);
                acc[m][n] = mfma16(Af[m][1], Bf[n][1], acc[m][n]);
            }
        #pragma unroll
        for (int m = 0; m < 4; ++m)
            #pragma unroll
            for (int n = 0; n < 3; ++n)
                #pragma unroll
                for (int r = 0; r < 4; ++r) {
                    int ac = m*16 + g*4 + r;
                    _Float16 hv = (_Float16)acc[m][n][r];
                    t2s[pl_c[n]*864 + ac*12 + k_c[n]] =
                        __builtin_bit_cast(unsigned short, hv);
                }
        lds_fence();

        uint32_t w3p[3][6];
        #pragma unroll
        for (int z = 0; z < 3; ++z) {
            const uint32_t* wr = w3f + ((size_t)pr*12 + z*4 + h3)*8;
            uint4 wa = *(const uint4*)wr;
            uint2 wb = *(const uint2*)(wr + 4);
            w3p[z][0]=wa.x; w3p[z][1]=wa.y; w3p[z][2]=wa.z; w3p[z][3]=wa.w;
            w3p[z][4]=wb.x; w3p[z][5]=wb.y;
        }
        const float4* brow = (const float4*)(biasr + ((size_t)pr*16 + h)*48);
        __hip_bfloat16* dst = pr == 0 ? Qb : pr == 1 ? Kb : Vr;
        const int pitch = pr == 0 ? QW : DP;
        unsigned short* drow = (unsigned short*)dst
            + ((size_t)(b3*NHc + h) * SP + s3) * pitch;
        #pragma unroll
        for (int half = 0; half < 2; ++half) {
            float od[24];
            #pragma unroll
            for (int j = 0; j < 6; ++j) {
                float4 bv = brow[half*6 + j];
                od[j*4+0]=bv.x; od[j*4+1]=bv.y; od[j*4+2]=bv.z; od[j*4+3]=bv.w;
            }
            #pragma unroll
            for (int xh = 0; xh < 2; ++xh) {
                int xq = half*2 + xh;
                #pragma unroll
                for (int yq = 0; yq < 4; ++yq) {
                    int a = xq*2 + (h >> 3), c = yq*2 + ((h >> 2) & 1);
                    int ac = a*8 + c;
                    const uint2* tp = (const uint2*)&t2s[plo*864 + ac*12];
                    uint2 q0 = tp[0], q1 = tp[1], q2 = tp[2];
                    #pragma unroll
                    for (int z = 0; z < 3; ++z) {
                        float a3 = od[xh*12 + yq*3 + z];
                        a3 = fdot2u(q0.x, w3p[z][0], a3);
                        a3 = fdot2u(q0.y, w3p[z][1], a3);
                        a3 = fdot2u(q1.x, w3p[z][2], a3);
                        a3 = fdot2u(q1.y, w3p[z][3], a3);
                        a3 = fdot2u(q2.x, w3p[z][4], a3);
                        a3 = fdot2u(q2.y, w3p[z][5], a3);
                        od[xh*12 + yq*3 + z] = a3;
                    }
                }
            }
            #pragma unroll
            for (int u = 0; u < 3; ++u) {
                uint32_t wd[4];
                #pragma unroll
                for (int q = 0; q < 4; ++q)
                    wd[q] = pkbf(od[u*8 + 2*q], od[u*8 + 2*q + 1]);
                *(uint4*)(drow + (half*3 + u)*8) = make_uint4(wd[0], wd[1], wd[2], wd[3]);
            }
        }
        lds_fence();
    }
}

// ---------------------------------------------------------------------------
// V transpose + pad fixups (unchanged).
// ---------------------------------------------------------------------------
__global__ __launch_bounds__(256) void vtrans(
    const __hip_bfloat16* __restrict__ Vr, __hip_bfloat16* __restrict__ Vt,
    __hip_bfloat16* __restrict__ Kb)
{
    __shared__ __align__(16) short Ls[64][72];
    const int t = threadIdx.x;
    const int bh = blockIdx.x, st = blockIdx.y;
    const __hip_bfloat16* src = Vr + ((size_t)bh * SP + st*64) * DP;
    for (int u = t; u < 512; u += 256) {
        int r = u >> 3, c = (u & 7) * 8;
        *(bf16x8*)&Ls[r][c] = *(const bf16x8*)(src + (size_t)r * DP + c);
    }
    __syncthreads();
    const unsigned short one_bf = 0x3F80;
    for (int u = t; u < 384; u += 256) {
        int dh = u >> 3, cb = (u & 7) * 8;
        int gcol = st*64 + cb;
        if (gcol >= Sc + 8) continue;
        union { unsigned short s[8]; bf16x8 v; } o;
        if (gcol >= Sc) {
            #pragma unroll
            for (int j = 0; j < 8; ++j) o.s[j] = 0;
        } else {
            #pragma unroll
            for (int j = 0; j < 8; ++j) o.s[j] = (unsigned short)Ls[cb + j][dh];
        }
        *(bf16x8*)(Vt + ((size_t)bh*64 + dh) * SP + st*64 + cb) = o.v;
    }
    if (t < 128) {
        int r = 48 + (t >> 3), cb = (t & 7) * 8;
        union { unsigned short s[8]; bf16x8 v; } o;
        #pragma unroll
        for (int j = 0; j < 8; ++j) {
            int col = st*64 + cb + j;
            o.s[j] = (r == 48 && col < Sc) ? one_bf : (unsigned short)0;
        }
        *(bf16x8*)(Vt + ((size_t)bh*64 + r) * SP + st*64 + cb) = o.v;
    }
    if (st == 9 && t < 64) {
        int r = 600 + (t >> 3), cb = (t & 7) * 8;
        union { unsigned short s[8]; bf16x8 v; } z;
        #pragma unroll
        for (int j = 0; j < 8; ++j) z.s[j] = 0;
        *(bf16x8*)(Kb + ((size_t)bh * SP + r) * DP + cb) = z.v;
    }
}

// ---------------------------------------------------------------------------
// softmax pack (unchanged)
// ---------------------------------------------------------------------------
static __device__ __forceinline__ void softmax_pack(
    const f32x16& sv, bf16x8& pf0, bf16x8& pf1)
{
    float p[16];
    #pragma unroll
    for (int r = 0; r < 16; ++r) p[r] = __expf(sv[r]);
    uint32_t Wa0, Wa1, Wa2, Wa3, Wb0, Wb1, Wb2, Wb3;
    Wa0 = pkbf(p[0], p[1]);   Wb0 = pkbf(p[2], p[3]);
    Wa1 = pkbf(p[4], p[5]);   Wb1 = pkbf(p[6], p[7]);
    Wa2 = pkbf(p[8], p[9]);   Wb2 = pkbf(p[10], p[11]);
    Wa3 = pkbf(p[12], p[13]); Wb3 = pkbf(p[14], p[15]);
    asm("v_permlane32_swap_b32 %0, %1" : "+v"(Wa0), "+v"(Wa1));
    asm("v_permlane32_swap_b32 %0, %1" : "+v"(Wb0), "+v"(Wb1));
    asm("v_permlane32_swap_b32 %0, %1" : "+v"(Wa2), "+v"(Wa3));
    asm("v_permlane32_swap_b32 %0, %1" : "+v"(Wb2), "+v"(Wb3));
    pf0 = __builtin_bit_cast(bf16x8, (u32x4){Wa0, Wb0, Wa1, Wb1});
    pf1 = __builtin_bit_cast(bf16x8, (u32x4){Wa2, Wb2, Wa3, Wb3});
}

// ---------------------------------------------------------------------------
// Attention (R15 form + T4 counted-vmcnt pipeline: issue stage(kt+1) BEFORE
// waiting, wait only for the oldest 8 loads = stage(kt); never drain to 0 in
// the main loop). grid = 2560 (XCD-chunked), block = 64
// ---------------------------------------------------------------------------
__global__ __launch_bounds__(64, 2) void attn_mfma(
    const __hip_bfloat16* __restrict__ Qb, const __hip_bfloat16* __restrict__ Kb,
    const __hip_bfloat16* __restrict__ Vt, float* __restrict__ Ob)
{
    __shared__ __align__(16) char Ks[2][4096];
    __shared__ __align__(16) char Vs[2][4096];
    const int l = threadIdx.x;
    const int q32 = l & 31, hl = l >> 5;
    const int bid = blockIdx.x;
    const int lg = (bid & 7) * 320 + (bid >> 3);     // XCD-chunked (2560%8==0)
    const int bh = lg / 5, qb = lg - bh * 5;
    const int b = bh >> 4, h = bh & 15;

    const char* Kbh = (const char*)(Kb + (size_t)bh * SP * DP);
    const char* Vbh = (const char*)(Vt + (size_t)bh * 64 * SP);

    const int krow = l >> 3;
    const char* ksrc = Kbh + krow*128 + (((l & 7)*16) ^ (krow << 4));
    const char* vsrc = Vbh + (size_t)(l >> 2)*(SP*2)
                     + (((l & 3) ^ ((l >> 3) & 3)) * 16);

    bf16x8 qf[4][3];
    #pragma unroll
    for (int f = 0; f < 4; ++f) {
        const __hip_bfloat16* Qp = Qb + ((size_t)bh*SP + qb*128 + f*32 + q32) * QW;
        #pragma unroll
        for (int ck = 0; ck < 3; ++ck)
            qf[f][ck] = *(const bf16x8*)(Qp + ck*16 + hl*8);
    }
    f32x16 acc[4][2];
    #pragma unroll
    for (int f = 0; f < 4; ++f) { acc[f][0] = fzero16(); acc[f][1] = fzero16(); }

    auto stage = [&](int kt, int bfi) {
        const char* ks = ksrc + (size_t)kt * 4096;
        const char* vs = vsrc + (size_t)kt * 64;
        #pragma unroll
        for (int i = 0; i < 4; ++i)
            gload_lds16(ks + i*1024, &Ks[bfi][i*1024]);
        #pragma unroll
        for (int i = 0; i < 4; ++i)
            gload_lds16(vs + (size_t)i*16*(SP*2), &Vs[bfi][i*1024]);
    };

    stage(0, 0);
    int bfi = 0;
    #pragma unroll 1
    for (int kt = 0; kt < NKT; ++kt) {
        // T4: issue next tile's loads FIRST, then wait only for the oldest 8
        // (= stage(kt)); stage(kt+1) stays in flight across this compute.
        // Buffer bfi^1 is free: its ds_reads completed in iteration kt-1.
        if (kt + 1 < NKT) {
            stage(kt + 1, bfi ^ 1);
            asm volatile("s_waitcnt vmcnt(8)" ::: "memory");
        } else {
            asm volatile("s_waitcnt vmcnt(0)" ::: "memory");
        }
        __builtin_amdgcn_sched_barrier(0);
        bf16x8 kf[3], vf[2][2];
        #pragma unroll
        for (int ck = 0; ck < 3; ++ck)
            kf[ck] = *(const bf16x8*)&Ks[bfi][q32*128 + ((ck*32 + hl*16) ^ ((q32 & 7) << 4))];
        #pragma unroll
        for (int db = 0; db < 2; ++db)
            #pragma unroll
            for (int c2 = 0; c2 < 2; ++c2)
                vf[db][c2] = *(const bf16x8*)&Vs[bfi][(db*32 + q32)*64
                                + ((c2*32 + hl*16) ^ (((q32 >> 1) & 3) << 4))];
        __builtin_amdgcn_s_setprio(1);
        #pragma unroll
        for (int f = 0; f < 4; ++f) {
            f32x16 s = fzero16();
            s = mfma32(kf[0], qf[f][0], s);
            s = mfma32(kf[1], qf[f][1], s);
            s = mfma32(kf[2], qf[f][2], s);
            bf16x8 pf0, pf1;
            softmax_pack(s, pf0, pf1);
            acc[f][0] = mfma32(vf[0][0], pf0, acc[f][0]);
            acc[f][0] = mfma32(vf[0][1], pf1, acc[f][0]);
            acc[f][1] = mfma32(vf[1][0], pf0, acc[f][1]);
            acc[f][1] = mfma32(vf[1][1], pf1, acc[f][1]);
        }
        __builtin_amdgcn_s_setprio(0);
        bfi ^= 1;
    }

    #pragma unroll
    for (int f = 0; f < 4; ++f) {
        float ls = acc[f][1][8];
        float other = __shfl_xor(ls, 32);
        float tot = hl ? other : ls;
        float inv = 1.f / tot;
        int q = qb*128 + f*32 + q32;
        if (q < Sc) {
            float* orow = Ob + ((size_t)b*Sc + q)*768 + h*48;
            #pragma unroll
            for (int rq = 0; rq < 4; ++rq) {
                int d0 = rq*8 + hl*4;
                float4 v4 = make_float4(acc[f][0][rq*4+0]*inv, acc[f][0][rq*4+1]*inv,
                                        acc[f][0][rq*4+2]*inv, acc[f][0][rq*4+3]*inv);
                *(float4*)(orow + d0) = v4;
            }
            #pragma unroll
            for (int rq = 0; rq < 2; ++rq) {
                int d0 = 32 + rq*8 + hl*4;
                float4 v4 = make_float4(acc[f][1][rq*4+0]*inv, acc[f][1][rq*4+1]*inv,
                                        acc[f][1][rq*4+2]*inv, acc[f][1][rq*4+3]*inv);
                *(float4*)(orow + d0) = v4;
            }
        }
    }
}

// ---------------------------------------------------------------------------
// Output TLE (unchanged R13 form)
// ---------------------------------------------------------------------------
__global__ __launch_bounds__(256, 3) void tle_out(
    const float* __restrict__ Oin, const float* __restrict__ w1g,
    const float* __restrict__ w2g, const float* __restrict__ w3g,
    const float* __restrict__ bias, float* __restrict__ out)
{
    __shared__ __align__(16) float xs[4][768];
    __shared__ __align__(16) unsigned short t1s[4][8][104];
    const int t = threadIdx.x;
    const int p = t >> 6, a = (t >> 3) & 7, c = t & 7;
    const int lane = t & 63;
    const int patch = blockIdx.x * 4 + p;
    for (int o4 = lane; o4 < 192; o4 += 64) {
        float4 v = *(const float4*)(Oin + (size_t)patch * 768 + o4*4);
        int h = o4 / 12, r = o4 - h*12;
        #pragma unroll
        for (int q = 0; q < 4; ++q) {
            int dh = r*4 + q;
            int xq = dh / 12, rem2 = dh - xq*12, yq = rem2 / 3, zq = rem2 - yq*3;
            int aa = xq*2 + (h >> 3), cc = yq*2 + ((h >> 2) & 1), dd = zq*4 + (h & 3);
            xs[p][aa*96 + cc*12 + dd] = ((const float*)&v)[q];
        }
    }
    float w1r[8], w2r[8];
    #pragma unroll
    for (int i = 0; i < 8; ++i) { w1r[i] = w1g[a*8 + i]; w2r[i] = w2g[c*8 + i]; }
    lds_fence();

    float s1[12];
    #pragma unroll
    for (int k = 0; k < 12; ++k) s1[k] = 0.f;
    #pragma unroll
    for (int i = 0; i < 8; ++i) {
        const float4* xr = (const float4*)&xs[p][i*96 + c*12];
        float4 v0 = xr[0], v1 = xr[1], v2 = xr[2];
        float wv = w1r[i];
        s1[0] += wv*v0.x; s1[1] += wv*v0.y; s1[2]  += wv*v0.z; s1[3]  += wv*v0.w;
        s1[4] += wv*v1.x; s1[5] += wv*v1.y; s1[6]  += wv*v1.z; s1[7]  += wv*v1.w;
        s1[8] += wv*v2.x; s1[9] += wv*v2.y; s1[10] += wv*v2.z; s1[11] += wv*v2.w;
    }
    {
        uint32_t pk[6];
        #pragma unroll
        for (int n = 0; n < 6; ++n) pk[n] = pkbf(s1[2*n], s1[2*n+1]);
        unsigned short* row = &t1s[p][a][0];
        *(uint2*)(row + c*12 + 0) = make_uint2(pk[0], pk[1]);
        *(uint2*)(row + c*12 + 4) = make_uint2(pk[2], pk[3]);
        *(uint2*)(row + c*12 + 8) = make_uint2(pk[4], pk[5]);
    }
    lds_fence();

    uint4 q[12];
    const uint4* t1p = (const uint4*)&t1s[p][a][0];
    #pragma unroll
    for (int n = 0; n < 12; ++n) q[n] = t1p[n];
    float t2r[12];
    #pragma unroll
    for (int k = 0; k < 12; ++k) t2r[k] = 0.f;
    #pragma unroll
    for (int j = 0; j < 8; ++j) {
        float wv = w2r[j];
        #pragma unroll
        for (int k = 0; k < 12; ++k) {
            int idx = j*12 + k;
            uint32_t ww = __builtin_bit_cast(u32x4, q[idx >> 3])[(idx >> 1) & 3];
            float xv = __builtin_bit_cast(float,
                (idx & 1) ? (ww & 0xffff0000u) : (ww << 16));
            t2r[k] += wv * xv;
        }
    }
    const float4* bp = (const float4*)(bias + a*96 + c*12);
    float4 b0 = bp[0], b1 = bp[1], b2 = bp[2];
    float bias_[12] = {b0.x,b0.y,b0.z,b0.w, b1.x,b1.y,b1.z,b1.w, b2.x,b2.y,b2.z,b2.w};
    float od[12];
    #pragma unroll
    for (int d = 0; d < 12; ++d) {
        const float4* wr = (const float4*)(w3g + d*12);
        float4 u0 = wr[0], u1 = wr[1], u2 = wr[2];
        od[d] = bias_[d]
            + t2r[0]*u0.x + t2r[1]*u0.y + t2r[2] *u0.z + t2r[3] *u0.w
            + t2r[4]*u1.x + t2r[5]*u1.y + t2r[6] *u1.z + t2r[7] *u1.w
            + t2r[8]*u2.x + t2r[9]*u2.y + t2r[10]*u2.z + t2r[11]*u2.w;
    }
    float4* op = (float4*)(out + (size_t)patch*768 + a*96 + c*12);
    op[0] = make_float4(od[0], od[1], od[2],  od[3]);
    op[1] = make_float4(od[4], od[5], od[6],  od[7]);
    op[2] = make_float4(od[8], od[9], od[10], od[11]);
}

extern "C" void kernel_launch(void* const* d_in, const int* in_sizes, int n_in,
                              void* d_out, int out_size, void* d_ws, size_t ws_size,
                              hipStream_t stream) {
    const float* x   = (const float*)d_in[0];
    const float* wq1 = (const float*)d_in[1];
    const float* wq2 = (const float*)d_in[2];
    const float* wq3 = (const float*)d_in[3];
    const float* bq  = (const float*)d_in[4];
    const float* wk1 = (const float*)d_in[5];
    const float* wk2 = (const float*)d_in[6];
    const float* wk3 = (const float*)d_in[7];
    const float* bk  = (const float*)d_in[8];
    const float* wv1 = (const float*)d_in[9];
    const float* wv2 = (const float*)d_in[10];
    const float* wv3 = (const float*)d_in[11];
    const float* bv  = (const float*)d_in[12];
    const float* wo1 = (const float*)d_in[13];
    const float* wo2 = (const float*)d_in[14];
    const float* wo3 = (const float*)d_in[15];
    const float* bo  = (const float*)d_in[16];
    float* out = (float*)d_out;

    char* ws = (char*)d_ws;
    const size_t SZ_Q  = (size_t)512 * SP * QW * 2;            // 31.5 MB
    const size_t SZ_K  = (size_t)512 * SP * DP * 2;            // 41.9 MB
    const size_t SZ_OB = (size_t)32 * 600 * 768 * 4;           // 59.0 MB
    __hip_bfloat16* Qb = (__hip_bfloat16*)ws;
    __hip_bfloat16* Kb = (__hip_bfloat16*)(ws + SZ_Q);
    __hip_bfloat16* Vr = (__hip_bfloat16*)(ws + SZ_Q + SZ_K);
    __hip_bfloat16* Vt = (__hip_bfloat16*)(ws + SZ_Q + 2*SZ_K);   // [512][64][640]
    float*          Ob = (float*)(ws + SZ_Q + 3*SZ_K);            // [32][600][768]
    char* tb = ws + SZ_Q + 3*SZ_K + SZ_OB;
    __hip_bfloat16* W12f  = (__hip_bfloat16*)tb;                  // 24576 B
    float*          biasr = (float*)(tb + 24576);                 //  9216 B
    uint32_t*       w3f   = (uint32_t*)(tb + 24576 + 9216);       //  1152 B

    prep<<<3, 256, 0, stream>>>(wq1, wq2, wq3, bq, wk1, wk2, wk3, bk,
                                wv1, wv2, wv3, bv, W12f, biasr, w3f);
    tle_qkv<<<Bc*Sc/4, 64, 0, stream>>>(x, W12f, biasr, w3f, Qb, Kb, Vr);
    vtrans<<<dim3(512, 10), 256, 0, stream>>>(Vr, Vt, Kb);
    attn_mfma<<<2560, 64, 0, stream>>>(Qb, Kb, Vt, Ob);
    tle_out<<<Bc*Sc/4, 256, 0, stream>>>(Ob, wo1, wo2, wo3, bo, out);
}

// Round 20
// 164.042 us; speedup vs baseline: 1.1015x; 1.1015x over previous
//
#include <hip/hip_runtime.h>
#include <hip/hip_bf16.h>
#include <cstdint>

#define Bc    32
#define Sc    600
#define NHc   16
#define SP    640            // padded seq rows (alloc)
#define NKT   19             // 19 key tiles of 32 = 608
#define DHc   48
#define DP    64             // K/V row width
#define QW    48             // Q row width
#define SCALEc 0.14433756729740643f   // 48^-0.5 (folded into Q at projection)

typedef __bf16    bf16x8 __attribute__((ext_vector_type(8)));
typedef float     f32x4  __attribute__((ext_vector_type(4)));
typedef float     f32x16 __attribute__((ext_vector_type(16)));
typedef uint32_t  u32x4  __attribute__((ext_vector_type(4)));
typedef _Float16  f16x2  __attribute__((ext_vector_type(2)));

static __device__ __forceinline__ f32x4 mfma16(bf16x8 a, bf16x8 b, f32x4 c) {
    return __builtin_amdgcn_mfma_f32_16x16x32_bf16(a, b, c, 0, 0, 0);
}
static __device__ __forceinline__ f32x16 mfma32(bf16x8 a, bf16x8 b, f32x16 c) {
    return __builtin_amdgcn_mfma_f32_32x32x16_bf16(a, b, c, 0, 0, 0);
}
static __device__ __forceinline__ float fdot2u(uint32_t a, uint32_t b, float c) {
    return __builtin_amdgcn_fdot2(__builtin_bit_cast(f16x2, a),
                                  __builtin_bit_cast(f16x2, b), c, false);
}
static __device__ __forceinline__ f32x16 fzero16() {
    f32x16 z;
    #pragma unroll
    for (int i = 0; i < 16; ++i) z[i] = 0.f;
    return z;
}
static __device__ __forceinline__ void gload_lds16(const void* g, void* l) {
    __builtin_amdgcn_global_load_lds(
        (const __attribute__((address_space(1))) unsigned int*)g,
        (__attribute__((address_space(3))) unsigned int*)l, 16, 0, 0);
}
static __device__ __forceinline__ void lds_fence() {
    asm volatile("s_waitcnt lgkmcnt(0)" ::: "memory");
}
static __device__ __forceinline__ uint32_t pkbf(float a, float b) {
    uint32_t r;
    asm("v_cvt_pk_bf16_f32 %0, %1, %2" : "=v"(r) : "v"(a), "v"(b));
    return r;
}

// ---------------------------------------------------------------------------
// Fused Q/K/V TLE v10 (R13 best form): od-split anti-spill, global weights,
// barrier-free wave-local fences, launch_bounds(256,3).
// grid = 1200 (16 patches/block), block = 256 (4 waves)
// ---------------------------------------------------------------------------
__global__ __launch_bounds__(256, 3) void tle_qkv(
    const float* __restrict__ x,
    const float* __restrict__ wq1, const float* __restrict__ wq2,
    const float* __restrict__ wq3, const float* __restrict__ bq,
    const float* __restrict__ wk1, const float* __restrict__ wk2,
    const float* __restrict__ wk3, const float* __restrict__ bk,
    const float* __restrict__ wv1, const float* __restrict__ wv2,
    const float* __restrict__ wv3, const float* __restrict__ bv,
    __hip_bfloat16* __restrict__ Qb, __hip_bfloat16* __restrict__ Kb,
    __hip_bfloat16* __restrict__ Vr)
{
    __shared__ __align__(16) char uni[16*864*2];          // 27648 B
    unsigned short* xb  = (unsigned short*)uni;           // [p][k*72 + ij]
    unsigned short* t2s = (unsigned short*)uni;           // [p][ac*12 + k] same slot
    const int t = threadIdx.x;
    const int patch0 = blockIdx.x * 16;

    {   // phase 1: x (f32, coalesced) -> xb transposed bf16 (own wave's patches)
        const int pl = t >> 4, ij0 = (t & 15) * 4;
        const float4* xg = (const float4*)(x + (size_t)(patch0 + pl) * 768 + ij0*12);
        float vv[4][12];
        #pragma unroll
        for (int ij = 0; ij < 4; ++ij) {
            float4 a = xg[ij*3+0], b = xg[ij*3+1], c = xg[ij*3+2];
            vv[ij][0]=a.x; vv[ij][1]=a.y; vv[ij][2]=a.z;  vv[ij][3]=a.w;
            vv[ij][4]=b.x; vv[ij][5]=b.y; vv[ij][6]=b.z;  vv[ij][7]=b.w;
            vv[ij][8]=c.x; vv[ij][9]=c.y; vv[ij][10]=c.z; vv[ij][11]=c.w;
        }
        #pragma unroll
        for (int k = 0; k < 12; ++k) {
            uint32_t lo = pkbf(vv[0][k], vv[1][k]);
            uint32_t hi = pkbf(vv[2][k], vv[3][k]);
            *(uint2*)&xb[pl*864 + k*72 + ij0] = make_uint2(lo, hi);
        }
    }
    lds_fence();   // xb (own patches) written -> readable by own wave

    const int l = t & 63, w = t >> 6;
    const int r16 = l & 15, g = l >> 4;

    // B-frags: persist across all 3 projections (6 ds_read_b128, own patches)
    bf16x8 Bf[3][2];
    int pl_c[3], k_c[3];
    #pragma unroll
    for (int n = 0; n < 3; ++n) {
        int col = n*16 + r16;
        int pp = col / 12, kk = col - pp*12;
        pl_c[n] = w*4 + pp; k_c[n] = kk;
        #pragma unroll
        for (int kh = 0; kh < 2; ++kh)
            Bf[n][kh] = *(const bf16x8*)&xb[pl_c[n]*864 + kk*72 + kh*32 + g*8];
    }
    lds_fence();   // xb consumed -> slots reusable as t2s by own wave

    const int plo = t >> 4, h = t & 15;            // stage3 mapping
    const int h1 = h >> 3, h2 = (h >> 2) & 1, h3 = h & 3;
    const int patch3 = patch0 + plo;
    const int b3 = patch3 / Sc, s3 = patch3 - b3*Sc;

    #pragma unroll 1
    for (int pr = 0; pr < 3; ++pr) {
        const float* w1 = pr == 0 ? wq1 : pr == 1 ? wk1 : wv1;
        const float* w2 = pr == 0 ? wq2 : pr == 1 ? wk2 : wv2;
        // ---- stage 1+2: MFMA ----
        float w2r[8];
        #pragma unroll
        for (int j = 0; j < 8; ++j) w2r[j] = w2[(r16 & 7)*8 + j];
        bf16x8 Af[4][2];
        #pragma unroll
        for (int m = 0; m < 4; ++m) {
            int a = 2*m + (r16 >> 3);
            #pragma unroll
            for (int kh = 0; kh < 2; ++kh) {
                float w1v = w1[a*8 + kh*4 + g];
                uint32_t wd[4];
                #pragma unroll
                for (int q = 0; q < 4; ++q)
                    wd[q] = pkbf(w1v*w2r[2*q], w1v*w2r[2*q+1]);
                Af[m][kh] = __builtin_bit_cast(bf16x8, (u32x4){wd[0],wd[1],wd[2],wd[3]});
            }
        }
        f32x4 acc[4][3];
        #pragma unroll
        for (int m = 0; m < 4; ++m)
            #pragma unroll
            for (int n = 0; n < 3; ++n) acc[m][n] = f32x4{0.f,0.f,0.f,0.f};
        #pragma unroll
        for (int m = 0; m < 4; ++m)
            #pragma unroll
            for (int n = 0; n < 3; ++n) {
                acc[m][n] = mfma16(Af[m][0], Bf[n][0], acc[m][n]);
                acc[m][n] = mfma16(Af[m][1], Bf[n][1], acc[m][n]);
            }
        // C -> t2s (f16): D col=lane&15 -> (p,k); row = m*16 + g*4 + r = ac
        #pragma unroll
        for (int m = 0; m < 4; ++m)
            #pragma unroll
            for (int n = 0; n < 3; ++n)
                #pragma unroll
                for (int r = 0; r < 4; ++r) {
                    int ac = m*16 + g*4 + r;
                    _Float16 hv = (_Float16)acc[m][n][r];
                    t2s[pl_c[n]*864 + ac*12 + k_c[n]] =
                        __builtin_bit_cast(unsigned short, hv);
                }
        lds_fence();   // own-wave t2s visible (in-order LDS per wave)

        // ---- stage 3: dot2 over k=12, two 24-value halves (anti-spill) ----
        const float* w3 = pr == 0 ? wq3 : pr == 1 ? wk3 : wv3;
        const float* bb = pr == 0 ? bq  : pr == 1 ? bk  : bv;
        uint32_t w3p[3][6];
        #pragma unroll
        for (int z = 0; z < 3; ++z) {
            const float* wr = w3 + (z*4 + h3)*12;
            #pragma unroll
            for (int q = 0; q < 6; ++q)
                w3p[z][q] = __builtin_bit_cast(uint32_t,
                    __builtin_amdgcn_cvt_pkrtz(wr[2*q], wr[2*q+1]));
        }
        __hip_bfloat16* dst = pr == 0 ? Qb : pr == 1 ? Kb : Vr;
        const int pitch = pr == 0 ? QW : DP;
        unsigned short* drow = (unsigned short*)dst
            + ((size_t)(b3*NHc + h) * SP + s3) * pitch;
        #pragma unroll
        for (int half = 0; half < 2; ++half) {
            float od[24];
            #pragma unroll
            for (int xh = 0; xh < 2; ++xh) {
                int xq = half*2 + xh;
                #pragma unroll
                for (int yq = 0; yq < 4; ++yq) {
                    int a = xq*2 + h1, c = yq*2 + h2;
                    int ac = a*8 + c;
                    const uint2* tp = (const uint2*)&t2s[plo*864 + ac*12];
                    uint2 q0 = tp[0], q1 = tp[1], q2 = tp[2];
                    const float* bp = bb + a*96 + c*12 + h3;
                    #pragma unroll
                    for (int z = 0; z < 3; ++z) {
                        float a3 = bp[z*4];
                        a3 = fdot2u(q0.x, w3p[z][0], a3);
                        a3 = fdot2u(q0.y, w3p[z][1], a3);
                        a3 = fdot2u(q1.x, w3p[z][2], a3);
                        a3 = fdot2u(q1.y, w3p[z][3], a3);
                        a3 = fdot2u(q2.x, w3p[z][4], a3);
                        a3 = fdot2u(q2.y, w3p[z][5], a3);
                        od[xh*12 + yq*3 + z] = a3;
                    }
                }
            }
            if (pr == 0) {
                #pragma unroll
                for (int i2 = 0; i2 < 24; ++i2) od[i2] *= SCALEc;
            }
            #pragma unroll
            for (int u = 0; u < 3; ++u) {
                uint32_t wd[4];
                #pragma unroll
                for (int q = 0; q < 4; ++q)
                    wd[q] = pkbf(od[u*8 + 2*q], od[u*8 + 2*q + 1]);
                *(uint4*)(drow + (half*3 + u)*8) = make_uint4(wd[0], wd[1], wd[2], wd[3]);
            }
        }
        lds_fence();   // stage3 reads done before next pr's t2s writes
    }
}

// ---------------------------------------------------------------------------
// V transpose + pad fixups (unchanged).
// ---------------------------------------------------------------------------
__global__ __launch_bounds__(256) void vtrans(
    const __hip_bfloat16* __restrict__ Vr, __hip_bfloat16* __restrict__ Vt,
    __hip_bfloat16* __restrict__ Kb)
{
    __shared__ __align__(16) short Ls[64][72];
    const int t = threadIdx.x;
    const int bh = blockIdx.x, st = blockIdx.y;
    const __hip_bfloat16* src = Vr + ((size_t)bh * SP + st*64) * DP;
    for (int u = t; u < 512; u += 256) {
        int r = u >> 3, c = (u & 7) * 8;
        *(bf16x8*)&Ls[r][c] = *(const bf16x8*)(src + (size_t)r * DP + c);
    }
    __syncthreads();
    const unsigned short one_bf = 0x3F80;
    for (int u = t; u < 384; u += 256) {
        int dh = u >> 3, cb = (u & 7) * 8;
        int gcol = st*64 + cb;
        if (gcol >= Sc + 8) continue;
        union { unsigned short s[8]; bf16x8 v; } o;
        if (gcol >= Sc) {
            #pragma unroll
            for (int j = 0; j < 8; ++j) o.s[j] = 0;
        } else {
            #pragma unroll
            for (int j = 0; j < 8; ++j) o.s[j] = (unsigned short)Ls[cb + j][dh];
        }
        *(bf16x8*)(Vt + ((size_t)bh*64 + dh) * SP + st*64 + cb) = o.v;
    }
    if (t < 128) {
        int r = 48 + (t >> 3), cb = (t & 7) * 8;
        union { unsigned short s[8]; bf16x8 v; } o;
        #pragma unroll
        for (int j = 0; j < 8; ++j) {
            int col = st*64 + cb + j;
            o.s[j] = (r == 48 && col < Sc) ? one_bf : (unsigned short)0;
        }
        *(bf16x8*)(Vt + ((size_t)bh*64 + r) * SP + st*64 + cb) = o.v;
    }
    if (st == 9 && t < 64) {
        int r = 600 + (t >> 3), cb = (t & 7) * 8;
        union { unsigned short s[8]; bf16x8 v; } z;
        #pragma unroll
        for (int j = 0; j < 8; ++j) z.s[j] = 0;
        *(bf16x8*)(Kb + ((size_t)bh * SP + r) * DP + cb) = z.v;
    }
}

// ---------------------------------------------------------------------------
// softmax pack (unchanged)
// ---------------------------------------------------------------------------
static __device__ __forceinline__ void softmax_pack(
    const f32x16& sv, bf16x8& pf0, bf16x8& pf1)
{
    float p[16];
    #pragma unroll
    for (int r = 0; r < 16; ++r) p[r] = __expf(sv[r]);
    uint32_t Wa0, Wa1, Wa2, Wa3, Wb0, Wb1, Wb2, Wb3;
    Wa0 = pkbf(p[0], p[1]);   Wb0 = pkbf(p[2], p[3]);
    Wa1 = pkbf(p[4], p[5]);   Wb1 = pkbf(p[6], p[7]);
    Wa2 = pkbf(p[8], p[9]);   Wb2 = pkbf(p[10], p[11]);
    Wa3 = pkbf(p[12], p[13]); Wb3 = pkbf(p[14], p[15]);
    asm("v_permlane32_swap_b32 %0, %1" : "+v"(Wa0), "+v"(Wa1));
    asm("v_permlane32_swap_b32 %0, %1" : "+v"(Wb0), "+v"(Wb1));
    asm("v_permlane32_swap_b32 %0, %1" : "+v"(Wa2), "+v"(Wa3));
    asm("v_permlane32_swap_b32 %0, %1" : "+v"(Wb2), "+v"(Wb3));
    pf0 = __builtin_bit_cast(bf16x8, (u32x4){Wa0, Wb0, Wa1, Wb1});
    pf1 = __builtin_bit_cast(bf16x8, (u32x4){Wa2, Wb2, Wa3, Wb3});
}

// ---------------------------------------------------------------------------
// Attention (R14 best form: 128q/wave, 1-wave blocks, V-slot swizzle,
// vmcnt(0)-at-top, stage-after-reads). grid = 2560 (XCD-chunked), block = 64
// ---------------------------------------------------------------------------
__global__ __launch_bounds__(64, 2) void attn_mfma(
    const __hip_bfloat16* __restrict__ Qb, const __hip_bfloat16* __restrict__ Kb,
    const __hip_bfloat16* __restrict__ Vt, float* __restrict__ Ob)
{
    __shared__ __align__(16) char Ks[2][4096];
    __shared__ __align__(16) char Vs[2][4096];
    const int l = threadIdx.x;
    const int q32 = l & 31, hl = l >> 5;
    const int bid = blockIdx.x;
    const int lg = (bid & 7) * 320 + (bid >> 3);     // XCD-chunked (2560%8==0)
    const int bh = lg / 5, qb = lg - bh * 5;
    const int b = bh >> 4, h = bh & 15;

    const char* Kbh = (const char*)(Kb + (size_t)bh * SP * DP);
    const char* Vbh = (const char*)(Vt + (size_t)bh * 64 * SP);

    const int krow = l >> 3;
    const char* ksrc = Kbh + krow*128 + (((l & 7)*16) ^ (krow << 4));
    // V: pre-swizzled global source; LDS slot (l&3) holds global slot
    // (l&3)^((l>>3)&3) so reads XOR with ((q32>>1)&3)<<4 are conflict-light.
    const char* vsrc = Vbh + (size_t)(l >> 2)*(SP*2)
                     + (((l & 3) ^ ((l >> 3) & 3)) * 16);

    bf16x8 qf[4][3];
    #pragma unroll
    for (int f = 0; f < 4; ++f) {
        const __hip_bfloat16* Qp = Qb + ((size_t)bh*SP + qb*128 + f*32 + q32) * QW;
        #pragma unroll
        for (int ck = 0; ck < 3; ++ck)
            qf[f][ck] = *(const bf16x8*)(Qp + ck*16 + hl*8);
    }
    f32x16 acc[4][2];
    #pragma unroll
    for (int f = 0; f < 4; ++f) { acc[f][0] = fzero16(); acc[f][1] = fzero16(); }

    auto stage = [&](int kt, int bfi) {
        const char* ks = ksrc + (size_t)kt * 4096;
        const char* vs = vsrc + (size_t)kt * 64;
        #pragma unroll
        for (int i = 0; i < 4; ++i)
            gload_lds16(ks + i*1024, &Ks[bfi][i*1024]);
        #pragma unroll
        for (int i = 0; i < 4; ++i)
            gload_lds16(vs + (size_t)i*16*(SP*2), &Vs[bfi][i*1024]);
    };

    stage(0, 0);
    int bfi = 0;
    #pragma unroll 1
    for (int kt = 0; kt < NKT; ++kt) {
        asm volatile("s_waitcnt vmcnt(0)" ::: "memory");
        __builtin_amdgcn_sched_barrier(0);
        bf16x8 kf[3], vf[2][2];
        #pragma unroll
        for (int ck = 0; ck < 3; ++ck)
            kf[ck] = *(const bf16x8*)&Ks[bfi][q32*128 + ((ck*32 + hl*16) ^ ((q32 & 7) << 4))];
        #pragma unroll
        for (int db = 0; db < 2; ++db)
            #pragma unroll
            for (int c2 = 0; c2 < 2; ++c2)
                vf[db][c2] = *(const bf16x8*)&Vs[bfi][(db*32 + q32)*64
                                + ((c2*32 + hl*16) ^ (((q32 >> 1) & 3) << 4))];
        if (kt + 1 < NKT) stage(kt + 1, bfi ^ 1);
        __builtin_amdgcn_s_setprio(1);
        #pragma unroll
        for (int f = 0; f < 4; ++f) {
            f32x16 s = fzero16();
            s = mfma32(kf[0], qf[f][0], s);
            s = mfma32(kf[1], qf[f][1], s);
            s = mfma32(kf[2], qf[f][2], s);
            bf16x8 pf0, pf1;
            softmax_pack(s, pf0, pf1);
            acc[f][0] = mfma32(vf[0][0], pf0, acc[f][0]);
            acc[f][0] = mfma32(vf[0][1], pf1, acc[f][0]);
            acc[f][1] = mfma32(vf[1][0], pf0, acc[f][1]);
            acc[f][1] = mfma32(vf[1][1], pf1, acc[f][1]);
        }
        __builtin_amdgcn_s_setprio(0);
        bfi ^= 1;
    }

    #pragma unroll
    for (int f = 0; f < 4; ++f) {
        float ls = acc[f][1][8];
        float other = __shfl_xor(ls, 32);
        float tot = hl ? other : ls;
        float inv = 1.f / tot;
        int q = qb*128 + f*32 + q32;
        if (q < Sc) {
            float* orow = Ob + ((size_t)b*Sc + q)*768 + h*48;
            #pragma unroll
            for (int rq = 0; rq < 4; ++rq) {
                int d0 = rq*8 + hl*4;
                float4 v4 = make_float4(acc[f][0][rq*4+0]*inv, acc[f][0][rq*4+1]*inv,
                                        acc[f][0][rq*4+2]*inv, acc[f][0][rq*4+3]*inv);
                *(float4*)(orow + d0) = v4;
            }
            #pragma unroll
            for (int rq = 0; rq < 2; ++rq) {
                int d0 = 32 + rq*8 + hl*4;
                float4 v4 = make_float4(acc[f][1][rq*4+0]*inv, acc[f][1][rq*4+1]*inv,
                                        acc[f][1][rq*4+2]*inv, acc[f][1][rq*4+3]*inv);
                *(float4*)(orow + d0) = v4;
            }
        }
    }
}

// ---------------------------------------------------------------------------
// Output TLE (R13 form: barrier-free, global weights)
// grid = 1200, block = 256
// ---------------------------------------------------------------------------
__global__ __launch_bounds__(256, 3) void tle_out(
    const float* __restrict__ Oin, const float* __restrict__ w1g,
    const float* __restrict__ w2g, const float* __restrict__ w3g,
    const float* __restrict__ bias, float* __restrict__ out)
{
    __shared__ __align__(16) float xs[4][768];
    __shared__ __align__(16) unsigned short t1s[4][8][104];
    const int t = threadIdx.x;
    const int p = t >> 6, a = (t >> 3) & 7, c = t & 7;
    const int lane = t & 63;
    const int patch = blockIdx.x * 4 + p;
    for (int o4 = lane; o4 < 192; o4 += 64) {
        float4 v = *(const float4*)(Oin + (size_t)patch * 768 + o4*4);
        int h = o4 / 12, r = o4 - h*12;
        #pragma unroll
        for (int q = 0; q < 4; ++q) {
            int dh = r*4 + q;
            int xq = dh / 12, rem2 = dh - xq*12, yq = rem2 / 3, zq = rem2 - yq*3;
            int aa = xq*2 + (h >> 3), cc = yq*2 + ((h >> 2) & 1), dd = zq*4 + (h & 3);
            xs[p][aa*96 + cc*12 + dd] = ((const float*)&v)[q];
        }
    }
    float w1r[8], w2r[8];
    #pragma unroll
    for (int i = 0; i < 8; ++i) { w1r[i] = w1g[a*8 + i]; w2r[i] = w2g[c*8 + i]; }
    lds_fence();

    float s1[12];
    #pragma unroll
    for (int k = 0; k < 12; ++k) s1[k] = 0.f;
    #pragma unroll
    for (int i = 0; i < 8; ++i) {
        const float4* xr = (const float4*)&xs[p][i*96 + c*12];
        float4 v0 = xr[0], v1 = xr[1], v2 = xr[2];
        float wv = w1r[i];
        s1[0] += wv*v0.x; s1[1] += wv*v0.y; s1[2]  += wv*v0.z; s1[3]  += wv*v0.w;
        s1[4] += wv*v1.x; s1[5] += wv*v1.y; s1[6]  += wv*v1.z; s1[7]  += wv*v1.w;
        s1[8] += wv*v2.x; s1[9] += wv*v2.y; s1[10] += wv*v2.z; s1[11] += wv*v2.w;
    }
    {
        uint32_t pk[6];
        #pragma unroll
        for (int n = 0; n < 6; ++n) pk[n] = pkbf(s1[2*n], s1[2*n+1]);
        unsigned short* row = &t1s[p][a][0];
        *(uint2*)(row + c*12 + 0) = make_uint2(pk[0], pk[1]);
        *(uint2*)(row + c*12 + 4) = make_uint2(pk[2], pk[3]);
        *(uint2*)(row + c*12 + 8) = make_uint2(pk[4], pk[5]);
    }
    lds_fence();

    uint4 q[12];
    const uint4* t1p = (const uint4*)&t1s[p][a][0];
    #pragma unroll
    for (int n = 0; n < 12; ++n) q[n] = t1p[n];
    float t2r[12];
    #pragma unroll
    for (int k = 0; k < 12; ++k) t2r[k] = 0.f;
    #pragma unroll
    for (int j = 0; j < 8; ++j) {
        float wv = w2r[j];
        #pragma unroll
        for (int k = 0; k < 12; ++k) {
            int idx = j*12 + k;
            uint32_t ww = __builtin_bit_cast(u32x4, q[idx >> 3])[(idx >> 1) & 3];
            float xv = __builtin_bit_cast(float,
                (idx & 1) ? (ww & 0xffff0000u) : (ww << 16));
            t2r[k] += wv * xv;
        }
    }
    const float4* bp = (const float4*)(bias + a*96 + c*12);
    float4 b0 = bp[0], b1 = bp[1], b2 = bp[2];
    float bias_[12] = {b0.x,b0.y,b0.z,b0.w, b1.x,b1.y,b1.z,b1.w, b2.x,b2.y,b2.z,b2.w};
    float od[12];
    #pragma unroll
    for (int d = 0; d < 12; ++d) {
        const float4* wr = (const float4*)(w3g + d*12);
        float4 u0 = wr[0], u1 = wr[1], u2 = wr[2];
        od[d] = bias_[d]
            + t2r[0]*u0.x + t2r[1]*u0.y + t2r[2] *u0.z + t2r[3] *u0.w
            + t2r[4]*u1.x + t2r[5]*u1.y + t2r[6] *u1.z + t2r[7] *u1.w
            + t2r[8]*u2.x + t2r[9]*u2.y + t2r[10]*u2.z + t2r[11]*u2.w;
    }
    float4* op = (float4*)(out + (size_t)patch*768 + a*96 + c*12);
    op[0] = make_float4(od[0], od[1], od[2],  od[3]);
    op[1] = make_float4(od[4], od[5], od[6],  od[7]);
    op[2] = make_float4(od[8], od[9], od[10], od[11]);
}

extern "C" void kernel_launch(void* const* d_in, const int* in_sizes, int n_in,
                              void* d_out, int out_size, void* d_ws, size_t ws_size,
                              hipStream_t stream) {
    const float* x   = (const float*)d_in[0];
    const float* wq1 = (const float*)d_in[1];
    const float* wq2 = (const float*)d_in[2];
    const float* wq3 = (const float*)d_in[3];
    const float* bq  = (const float*)d_in[4];
    const float* wk1 = (const float*)d_in[5];
    const float* wk2 = (const float*)d_in[6];
    const float* wk3 = (const float*)d_in[7];
    const float* bk  = (const float*)d_in[8];
    const float* wv1 = (const float*)d_in[9];
    const float* wv2 = (const float*)d_in[10];
    const float* wv3 = (const float*)d_in[11];
    const float* bv  = (const float*)d_in[12];
    const float* wo1 = (const float*)d_in[13];
    const float* wo2 = (const float*)d_in[14];
    const float* wo3 = (const float*)d_in[15];
    const float* bo  = (const float*)d_in[16];
    float* out = (float*)d_out;

    char* ws = (char*)d_ws;
    const size_t SZ_Q  = (size_t)512 * SP * QW * 2;            // 31.5 MB
    const size_t SZ_K  = (size_t)512 * SP * DP * 2;            // 41.9 MB
    __hip_bfloat16* Qb = (__hip_bfloat16*)ws;
    __hip_bfloat16* Kb = (__hip_bfloat16*)(ws + SZ_Q);
    __hip_bfloat16* Vr = (__hip_bfloat16*)(ws + SZ_Q + SZ_K);
    __hip_bfloat16* Vt = (__hip_bfloat16*)(ws + SZ_Q + 2*SZ_K);   // [512][64][640]
    float*          Ob = (float*)(ws + SZ_Q + 3*SZ_K);            // [32][600][768]

    tle_qkv<<<Bc*Sc/16, 256, 0, stream>>>(x, wq1, wq2, wq3, bq,
                                          wk1, wk2, wk3, bk,
                                          wv1, wv2, wv3, bv, Qb, Kb, Vr);
    vtrans<<<dim3(512, 10), 256, 0, stream>>>(Vr, Vt, Kb);
    attn_mfma<<<2560, 64, 0, stream>>>(Qb, Kb, Vt, Ob);
    tle_out<<<Bc*Sc/4, 256, 0, stream>>>(Ob, wo1, wo2, wo3, bo, out);
}

// Round 21
// 159.612 us; speedup vs baseline: 1.1321x; 1.0278x over previous
//
#include <hip/hip_runtime.h>
#include <hip/hip_bf16.h>
#include <cstdint>

#define Bc    32
#define Sc    600
#define NHc   16
#define SP    640            // padded seq rows (alloc)
#define NKT   19             // 19 key tiles of 32 = 608
#define DHc   48
#define DP    64             // K/V row width
#define QW    48             // Q row width
#define SCALEc 0.14433756729740643f   // 48^-0.5 (folded into Q at projection)

typedef __bf16    bf16x8 __attribute__((ext_vector_type(8)));
typedef float     f32x4  __attribute__((ext_vector_type(4)));
typedef float     f32x16 __attribute__((ext_vector_type(16)));
typedef uint32_t  u32x4  __attribute__((ext_vector_type(4)));
typedef _Float16  f16x2  __attribute__((ext_vector_type(2)));

static __device__ __forceinline__ f32x4 mfma16(bf16x8 a, bf16x8 b, f32x4 c) {
    return __builtin_amdgcn_mfma_f32_16x16x32_bf16(a, b, c, 0, 0, 0);
}
static __device__ __forceinline__ f32x16 mfma32(bf16x8 a, bf16x8 b, f32x16 c) {
    return __builtin_amdgcn_mfma_f32_32x32x16_bf16(a, b, c, 0, 0, 0);
}
static __device__ __forceinline__ float fdot2u(uint32_t a, uint32_t b, float c) {
    return __builtin_amdgcn_fdot2(__builtin_bit_cast(f16x2, a),
                                  __builtin_bit_cast(f16x2, b), c, false);
}
static __device__ __forceinline__ f32x16 fzero16() {
    f32x16 z;
    #pragma unroll
    for (int i = 0; i < 16; ++i) z[i] = 0.f;
    return z;
}
static __device__ __forceinline__ void gload_lds16(const void* g, void* l) {
    __builtin_amdgcn_global_load_lds(
        (const __attribute__((address_space(1))) unsigned int*)g,
        (__attribute__((address_space(3))) unsigned int*)l, 16, 0, 0);
}
static __device__ __forceinline__ void lds_fence() {
    asm volatile("s_waitcnt lgkmcnt(0)" ::: "memory");
}
static __device__ __forceinline__ uint32_t pkbf(float a, float b) {
    uint32_t r;
    asm("v_cvt_pk_bf16_f32 %0, %1, %2" : "=v"(r) : "v"(a), "v"(b));
    return r;
}

// ---------------------------------------------------------------------------
// Fused Q/K/V TLE v10 (R13/R20 best form): od-split anti-spill, global
// weights, barrier-free wave-local fences, launch_bounds(256,3).
// grid = 1200 (16 patches/block), block = 256 (4 waves)
// ---------------------------------------------------------------------------
__global__ __launch_bounds__(256, 3) void tle_qkv(
    const float* __restrict__ x,
    const float* __restrict__ wq1, const float* __restrict__ wq2,
    const float* __restrict__ wq3, const float* __restrict__ bq,
    const float* __restrict__ wk1, const float* __restrict__ wk2,
    const float* __restrict__ wk3, const float* __restrict__ bk,
    const float* __restrict__ wv1, const float* __restrict__ wv2,
    const float* __restrict__ wv3, const float* __restrict__ bv,
    __hip_bfloat16* __restrict__ Qb, __hip_bfloat16* __restrict__ Kb,
    __hip_bfloat16* __restrict__ Vr)
{
    __shared__ __align__(16) char uni[16*864*2];          // 27648 B
    unsigned short* xb  = (unsigned short*)uni;           // [p][k*72 + ij]
    unsigned short* t2s = (unsigned short*)uni;           // [p][ac*12 + k] same slot
    const int t = threadIdx.x;
    const int patch0 = blockIdx.x * 16;

    {   // phase 1: x (f32, coalesced) -> xb transposed bf16 (own wave's patches)
        const int pl = t >> 4, ij0 = (t & 15) * 4;
        const float4* xg = (const float4*)(x + (size_t)(patch0 + pl) * 768 + ij0*12);
        float vv[4][12];
        #pragma unroll
        for (int ij = 0; ij < 4; ++ij) {
            float4 a = xg[ij*3+0], b = xg[ij*3+1], c = xg[ij*3+2];
            vv[ij][0]=a.x; vv[ij][1]=a.y; vv[ij][2]=a.z;  vv[ij][3]=a.w;
            vv[ij][4]=b.x; vv[ij][5]=b.y; vv[ij][6]=b.z;  vv[ij][7]=b.w;
            vv[ij][8]=c.x; vv[ij][9]=c.y; vv[ij][10]=c.z; vv[ij][11]=c.w;
        }
        #pragma unroll
        for (int k = 0; k < 12; ++k) {
            uint32_t lo = pkbf(vv[0][k], vv[1][k]);
            uint32_t hi = pkbf(vv[2][k], vv[3][k]);
            *(uint2*)&xb[pl*864 + k*72 + ij0] = make_uint2(lo, hi);
        }
    }
    lds_fence();   // xb (own patches) written -> readable by own wave

    const int l = t & 63, w = t >> 6;
    const int r16 = l & 15, g = l >> 4;

    // B-frags: persist across all 3 projections (6 ds_read_b128, own patches)
    bf16x8 Bf[3][2];
    int pl_c[3], k_c[3];
    #pragma unroll
    for (int n = 0; n < 3; ++n) {
        int col = n*16 + r16;
        int pp = col / 12, kk = col - pp*12;
        pl_c[n] = w*4 + pp; k_c[n] = kk;
        #pragma unroll
        for (int kh = 0; kh < 2; ++kh)
            Bf[n][kh] = *(const bf16x8*)&xb[pl_c[n]*864 + kk*72 + kh*32 + g*8];
    }
    lds_fence();   // xb consumed -> slots reusable as t2s by own wave

    const int plo = t >> 4, h = t & 15;            // stage3 mapping
    const int h1 = h >> 3, h2 = (h >> 2) & 1, h3 = h & 3;
    const int patch3 = patch0 + plo;
    const int b3 = patch3 / Sc, s3 = patch3 - b3*Sc;

    #pragma unroll 1
    for (int pr = 0; pr < 3; ++pr) {
        const float* w1 = pr == 0 ? wq1 : pr == 1 ? wk1 : wv1;
        const float* w2 = pr == 0 ? wq2 : pr == 1 ? wk2 : wv2;
        // ---- stage 1+2: MFMA ----
        float w2r[8];
        #pragma unroll
        for (int j = 0; j < 8; ++j) w2r[j] = w2[(r16 & 7)*8 + j];
        bf16x8 Af[4][2];
        #pragma unroll
        for (int m = 0; m < 4; ++m) {
            int a = 2*m + (r16 >> 3);
            #pragma unroll
            for (int kh = 0; kh < 2; ++kh) {
                float w1v = w1[a*8 + kh*4 + g];
                uint32_t wd[4];
                #pragma unroll
                for (int q = 0; q < 4; ++q)
                    wd[q] = pkbf(w1v*w2r[2*q], w1v*w2r[2*q+1]);
                Af[m][kh] = __builtin_bit_cast(bf16x8, (u32x4){wd[0],wd[1],wd[2],wd[3]});
            }
        }
        f32x4 acc[4][3];
        #pragma unroll
        for (int m = 0; m < 4; ++m)
            #pragma unroll
            for (int n = 0; n < 3; ++n) acc[m][n] = f32x4{0.f,0.f,0.f,0.f};
        #pragma unroll
        for (int m = 0; m < 4; ++m)
            #pragma unroll
            for (int n = 0; n < 3; ++n) {
                acc[m][n] = mfma16(Af[m][0], Bf[n][0], acc[m][n]);
                acc[m][n] = mfma16(Af[m][1], Bf[n][1], acc[m][n]);
            }
        // C -> t2s (f16): D col=lane&15 -> (p,k); row = m*16 + g*4 + r = ac
        #pragma unroll
        for (int m = 0; m < 4; ++m)
            #pragma unroll
            for (int n = 0; n < 3; ++n)
                #pragma unroll
                for (int r = 0; r < 4; ++r) {
                    int ac = m*16 + g*4 + r;
                    _Float16 hv = (_Float16)acc[m][n][r];
                    t2s[pl_c[n]*864 + ac*12 + k_c[n]] =
                        __builtin_bit_cast(unsigned short, hv);
                }
        lds_fence();   // own-wave t2s visible (in-order LDS per wave)

        // ---- stage 3: dot2 over k=12, two 24-value halves (anti-spill) ----
        const float* w3 = pr == 0 ? wq3 : pr == 1 ? wk3 : wv3;
        const float* bb = pr == 0 ? bq  : pr == 1 ? bk  : bv;
        uint32_t w3p[3][6];
        #pragma unroll
        for (int z = 0; z < 3; ++z) {
            const float* wr = w3 + (z*4 + h3)*12;
            #pragma unroll
            for (int q = 0; q < 6; ++q)
                w3p[z][q] = __builtin_bit_cast(uint32_t,
                    __builtin_amdgcn_cvt_pkrtz(wr[2*q], wr[2*q+1]));
        }
        __hip_bfloat16* dst = pr == 0 ? Qb : pr == 1 ? Kb : Vr;
        const int pitch = pr == 0 ? QW : DP;
        unsigned short* drow = (unsigned short*)dst
            + ((size_t)(b3*NHc + h) * SP + s3) * pitch;
        #pragma unroll
        for (int half = 0; half < 2; ++half) {
            float od[24];
            #pragma unroll
            for (int xh = 0; xh < 2; ++xh) {
                int xq = half*2 + xh;
                #pragma unroll
                for (int yq = 0; yq < 4; ++yq) {
                    int a = xq*2 + h1, c = yq*2 + h2;
                    int ac = a*8 + c;
                    const uint2* tp = (const uint2*)&t2s[plo*864 + ac*12];
                    uint2 q0 = tp[0], q1 = tp[1], q2 = tp[2];
                    const float* bp = bb + a*96 + c*12 + h3;
                    #pragma unroll
                    for (int z = 0; z < 3; ++z) {
                        float a3 = bp[z*4];
                        a3 = fdot2u(q0.x, w3p[z][0], a3);
                        a3 = fdot2u(q0.y, w3p[z][1], a3);
                        a3 = fdot2u(q1.x, w3p[z][2], a3);
                        a3 = fdot2u(q1.y, w3p[z][3], a3);
                        a3 = fdot2u(q2.x, w3p[z][4], a3);
                        a3 = fdot2u(q2.y, w3p[z][5], a3);
                        od[xh*12 + yq*3 + z] = a3;
                    }
                }
            }
            if (pr == 0) {
                #pragma unroll
                for (int i2 = 0; i2 < 24; ++i2) od[i2] *= SCALEc;
            }
            #pragma unroll
            for (int u = 0; u < 3; ++u) {
                uint32_t wd[4];
                #pragma unroll
                for (int q = 0; q < 4; ++q)
                    wd[q] = pkbf(od[u*8 + 2*q], od[u*8 + 2*q + 1]);
                *(uint4*)(drow + (half*3 + u)*8) = make_uint4(wd[0], wd[1], wd[2], wd[3]);
            }
        }
        lds_fence();   // stage3 reads done before next pr's t2s writes
    }
}

// ---------------------------------------------------------------------------
// V transpose + pad fixups (unchanged).
// ---------------------------------------------------------------------------
__global__ __launch_bounds__(256) void vtrans(
    const __hip_bfloat16* __restrict__ Vr, __hip_bfloat16* __restrict__ Vt,
    __hip_bfloat16* __restrict__ Kb)
{
    __shared__ __align__(16) short Ls[64][72];
    const int t = threadIdx.x;
    const int bh = blockIdx.x, st = blockIdx.y;
    const __hip_bfloat16* src = Vr + ((size_t)bh * SP + st*64) * DP;
    for (int u = t; u < 512; u += 256) {
        int r = u >> 3, c = (u & 7) * 8;
        *(bf16x8*)&Ls[r][c] = *(const bf16x8*)(src + (size_t)r * DP + c);
    }
    __syncthreads();
    const unsigned short one_bf = 0x3F80;
    for (int u = t; u < 384; u += 256) {
        int dh = u >> 3, cb = (u & 7) * 8;
        int gcol = st*64 + cb;
        if (gcol >= Sc + 8) continue;
        union { unsigned short s[8]; bf16x8 v; } o;
        if (gcol >= Sc) {
            #pragma unroll
            for (int j = 0; j < 8; ++j) o.s[j] = 0;
        } else {
            #pragma unroll
            for (int j = 0; j < 8; ++j) o.s[j] = (unsigned short)Ls[cb + j][dh];
        }
        *(bf16x8*)(Vt + ((size_t)bh*64 + dh) * SP + st*64 + cb) = o.v;
    }
    if (t < 128) {
        int r = 48 + (t >> 3), cb = (t & 7) * 8;
        union { unsigned short s[8]; bf16x8 v; } o;
        #pragma unroll
        for (int j = 0; j < 8; ++j) {
            int col = st*64 + cb + j;
            o.s[j] = (r == 48 && col < Sc) ? one_bf : (unsigned short)0;
        }
        *(bf16x8*)(Vt + ((size_t)bh*64 + r) * SP + st*64 + cb) = o.v;
    }
    if (st == 9 && t < 64) {
        int r = 600 + (t >> 3), cb = (t & 7) * 8;
        union { unsigned short s[8]; bf16x8 v; } z;
        #pragma unroll
        for (int j = 0; j < 8; ++j) z.s[j] = 0;
        *(bf16x8*)(Kb + ((size_t)bh * SP + r) * DP + cb) = z.v;
    }
}

// ---------------------------------------------------------------------------
// softmax pack (unchanged)
// ---------------------------------------------------------------------------
static __device__ __forceinline__ void softmax_pack(
    const f32x16& sv, bf16x8& pf0, bf16x8& pf1)
{
    float p[16];
    #pragma unroll
    for (int r = 0; r < 16; ++r) p[r] = __expf(sv[r]);
    uint32_t Wa0, Wa1, Wa2, Wa3, Wb0, Wb1, Wb2, Wb3;
    Wa0 = pkbf(p[0], p[1]);   Wb0 = pkbf(p[2], p[3]);
    Wa1 = pkbf(p[4], p[5]);   Wb1 = pkbf(p[6], p[7]);
    Wa2 = pkbf(p[8], p[9]);   Wb2 = pkbf(p[10], p[11]);
    Wa3 = pkbf(p[12], p[13]); Wb3 = pkbf(p[14], p[15]);
    asm("v_permlane32_swap_b32 %0, %1" : "+v"(Wa0), "+v"(Wa1));
    asm("v_permlane32_swap_b32 %0, %1" : "+v"(Wb0), "+v"(Wb1));
    asm("v_permlane32_swap_b32 %0, %1" : "+v"(Wa2), "+v"(Wa3));
    asm("v_permlane32_swap_b32 %0, %1" : "+v"(Wb2), "+v"(Wb3));
    pf0 = __builtin_bit_cast(bf16x8, (u32x4){Wa0, Wb0, Wa1, Wb1});
    pf1 = __builtin_bit_cast(bf16x8, (u32x4){Wa2, Wb2, Wa3, Wb3});
}

// ---------------------------------------------------------------------------
// Attention (R14/R20 best form; Ob now bf16 -> epilogue packs with cvt_pk,
// halving O-intermediate HBM traffic). grid = 2560 (XCD-chunked), block = 64
// ---------------------------------------------------------------------------
__global__ __launch_bounds__(64, 2) void attn_mfma(
    const __hip_bfloat16* __restrict__ Qb, const __hip_bfloat16* __restrict__ Kb,
    const __hip_bfloat16* __restrict__ Vt, __hip_bfloat16* __restrict__ Ob)
{
    __shared__ __align__(16) char Ks[2][4096];
    __shared__ __align__(16) char Vs[2][4096];
    const int l = threadIdx.x;
    const int q32 = l & 31, hl = l >> 5;
    const int bid = blockIdx.x;
    const int lg = (bid & 7) * 320 + (bid >> 3);     // XCD-chunked (2560%8==0)
    const int bh = lg / 5, qb = lg - bh * 5;
    const int b = bh >> 4, h = bh & 15;

    const char* Kbh = (const char*)(Kb + (size_t)bh * SP * DP);
    const char* Vbh = (const char*)(Vt + (size_t)bh * 64 * SP);

    const int krow = l >> 3;
    const char* ksrc = Kbh + krow*128 + (((l & 7)*16) ^ (krow << 4));
    const char* vsrc = Vbh + (size_t)(l >> 2)*(SP*2)
                     + (((l & 3) ^ ((l >> 3) & 3)) * 16);

    bf16x8 qf[4][3];
    #pragma unroll
    for (int f = 0; f < 4; ++f) {
        const __hip_bfloat16* Qp = Qb + ((size_t)bh*SP + qb*128 + f*32 + q32) * QW;
        #pragma unroll
        for (int ck = 0; ck < 3; ++ck)
            qf[f][ck] = *(const bf16x8*)(Qp + ck*16 + hl*8);
    }
    f32x16 acc[4][2];
    #pragma unroll
    for (int f = 0; f < 4; ++f) { acc[f][0] = fzero16(); acc[f][1] = fzero16(); }

    auto stage = [&](int kt, int bfi) {
        const char* ks = ksrc + (size_t)kt * 4096;
        const char* vs = vsrc + (size_t)kt * 64;
        #pragma unroll
        for (int i = 0; i < 4; ++i)
            gload_lds16(ks + i*1024, &Ks[bfi][i*1024]);
        #pragma unroll
        for (int i = 0; i < 4; ++i)
            gload_lds16(vs + (size_t)i*16*(SP*2), &Vs[bfi][i*1024]);
    };

    stage(0, 0);
    int bfi = 0;
    #pragma unroll 1
    for (int kt = 0; kt < NKT; ++kt) {
        asm volatile("s_waitcnt vmcnt(0)" ::: "memory");
        __builtin_amdgcn_sched_barrier(0);
        bf16x8 kf[3], vf[2][2];
        #pragma unroll
        for (int ck = 0; ck < 3; ++ck)
            kf[ck] = *(const bf16x8*)&Ks[bfi][q32*128 + ((ck*32 + hl*16) ^ ((q32 & 7) << 4))];
        #pragma unroll
        for (int db = 0; db < 2; ++db)
            #pragma unroll
            for (int c2 = 0; c2 < 2; ++c2)
                vf[db][c2] = *(const bf16x8*)&Vs[bfi][(db*32 + q32)*64
                                + ((c2*32 + hl*16) ^ (((q32 >> 1) & 3) << 4))];
        if (kt + 1 < NKT) stage(kt + 1, bfi ^ 1);
        __builtin_amdgcn_s_setprio(1);
        #pragma unroll
        for (int f = 0; f < 4; ++f) {
            f32x16 s = fzero16();
            s = mfma32(kf[0], qf[f][0], s);
            s = mfma32(kf[1], qf[f][1], s);
            s = mfma32(kf[2], qf[f][2], s);
            bf16x8 pf0, pf1;
            softmax_pack(s, pf0, pf1);
            acc[f][0] = mfma32(vf[0][0], pf0, acc[f][0]);
            acc[f][0] = mfma32(vf[0][1], pf1, acc[f][0]);
            acc[f][1] = mfma32(vf[1][0], pf0, acc[f][1]);
            acc[f][1] = mfma32(vf[1][1], pf1, acc[f][1]);
        }
        __builtin_amdgcn_s_setprio(0);
        bfi ^= 1;
    }

    #pragma unroll
    for (int f = 0; f < 4; ++f) {
        float ls = acc[f][1][8];
        float other = __shfl_xor(ls, 32);
        float tot = hl ? other : ls;
        float inv = 1.f / tot;
        int q = qb*128 + f*32 + q32;
        if (q < Sc) {
            unsigned short* orow = (unsigned short*)Ob + ((size_t)b*Sc + q)*768 + h*48;
            #pragma unroll
            for (int rq = 0; rq < 4; ++rq) {
                int d0 = rq*8 + hl*4;
                uint32_t w0 = pkbf(acc[f][0][rq*4+0]*inv, acc[f][0][rq*4+1]*inv);
                uint32_t w1 = pkbf(acc[f][0][rq*4+2]*inv, acc[f][0][rq*4+3]*inv);
                *(uint2*)(orow + d0) = make_uint2(w0, w1);
            }
            #pragma unroll
            for (int rq = 0; rq < 2; ++rq) {
                int d0 = 32 + rq*8 + hl*4;
                uint32_t w0 = pkbf(acc[f][1][rq*4+0]*inv, acc[f][1][rq*4+1]*inv);
                uint32_t w1 = pkbf(acc[f][1][rq*4+2]*inv, acc[f][1][rq*4+3]*inv);
                *(uint2*)(orow + d0) = make_uint2(w0, w1);
            }
        }
    }
}

// ---------------------------------------------------------------------------
// Output TLE (R13 form; Oin now bf16 -> gather reads uint4 of 8 bf16)
// grid = 1200, block = 256
// ---------------------------------------------------------------------------
__global__ __launch_bounds__(256, 3) void tle_out(
    const __hip_bfloat16* __restrict__ Oin, const float* __restrict__ w1g,
    const float* __restrict__ w2g, const float* __restrict__ w3g,
    const float* __restrict__ bias, float* __restrict__ out)
{
    __shared__ __align__(16) float xs[4][768];
    __shared__ __align__(16) unsigned short t1s[4][8][104];
    const int t = threadIdx.x;
    const int p = t >> 6, a = (t >> 3) & 7, c = t & 7;
    const int lane = t & 63;
    const int patch = blockIdx.x * 4 + p;
    // gather heads -> xs: 96 units of 8 bf16 (one uint4 each)
    for (int o8 = lane; o8 < 96; o8 += 64) {
        uint4 v = *(const uint4*)((const unsigned short*)Oin
                                  + (size_t)patch * 768 + o8*8);
        int h = o8 / 6, r8 = o8 - h*6;
        const uint32_t wds[4] = {v.x, v.y, v.z, v.w};
        #pragma unroll
        for (int j = 0; j < 8; ++j) {
            int dh = r8*8 + j;
            uint32_t ww = wds[j >> 1];
            float xv = __builtin_bit_cast(float,
                (j & 1) ? (ww & 0xffff0000u) : (ww << 16));
            int xq = dh / 12, rem2 = dh - xq*12, yq = rem2 / 3, zq = rem2 - yq*3;
            int aa = xq*2 + (h >> 3), cc = yq*2 + ((h >> 2) & 1), dd = zq*4 + (h & 3);
            xs[p][aa*96 + cc*12 + dd] = xv;
        }
    }
    float w1r[8], w2r[8];
    #pragma unroll
    for (int i = 0; i < 8; ++i) { w1r[i] = w1g[a*8 + i]; w2r[i] = w2g[c*8 + i]; }
    lds_fence();

    float s1[12];
    #pragma unroll
    for (int k = 0; k < 12; ++k) s1[k] = 0.f;
    #pragma unroll
    for (int i = 0; i < 8; ++i) {
        const float4* xr = (const float4*)&xs[p][i*96 + c*12];
        float4 v0 = xr[0], v1 = xr[1], v2 = xr[2];
        float wv = w1r[i];
        s1[0] += wv*v0.x; s1[1] += wv*v0.y; s1[2]  += wv*v0.z; s1[3]  += wv*v0.w;
        s1[4] += wv*v1.x; s1[5] += wv*v1.y; s1[6]  += wv*v1.z; s1[7]  += wv*v1.w;
        s1[8] += wv*v2.x; s1[9] += wv*v2.y; s1[10] += wv*v2.z; s1[11] += wv*v2.w;
    }
    {
        uint32_t pk[6];
        #pragma unroll
        for (int n = 0; n < 6; ++n) pk[n] = pkbf(s1[2*n], s1[2*n+1]);
        unsigned short* row = &t1s[p][a][0];
        *(uint2*)(row + c*12 + 0) = make_uint2(pk[0], pk[1]);
        *(uint2*)(row + c*12 + 4) = make_uint2(pk[2], pk[3]);
        *(uint2*)(row + c*12 + 8) = make_uint2(pk[4], pk[5]);
    }
    lds_fence();

    uint4 q[12];
    const uint4* t1p = (const uint4*)&t1s[p][a][0];
    #pragma unroll
    for (int n = 0; n < 12; ++n) q[n] = t1p[n];
    float t2r[12];
    #pragma unroll
    for (int k = 0; k < 12; ++k) t2r[k] = 0.f;
    #pragma unroll
    for (int j = 0; j < 8; ++j) {
        float wv = w2r[j];
        #pragma unroll
        for (int k = 0; k < 12; ++k) {
            int idx = j*12 + k;
            uint32_t ww = __builtin_bit_cast(u32x4, q[idx >> 3])[(idx >> 1) & 3];
            float xv = __builtin_bit_cast(float,
                (idx & 1) ? (ww & 0xffff0000u) : (ww << 16));
            t2r[k] += wv * xv;
        }
    }
    const float4* bp = (const float4*)(bias + a*96 + c*12);
    float4 b0 = bp[0], b1 = bp[1], b2 = bp[2];
    float bias_[12] = {b0.x,b0.y,b0.z,b0.w, b1.x,b1.y,b1.z,b1.w, b2.x,b2.y,b2.z,b2.w};
    float od[12];
    #pragma unroll
    for (int d = 0; d < 12; ++d) {
        const float4* wr = (const float4*)(w3g + d*12);
        float4 u0 = wr[0], u1 = wr[1], u2 = wr[2];
        od[d] = bias_[d]
            + t2r[0]*u0.x + t2r[1]*u0.y + t2r[2] *u0.z + t2r[3] *u0.w
            + t2r[4]*u1.x + t2r[5]*u1.y + t2r[6] *u1.z + t2r[7] *u1.w
            + t2r[8]*u2.x + t2r[9]*u2.y + t2r[10]*u2.z + t2r[11]*u2.w;
    }
    float4* op = (float4*)(out + (size_t)patch*768 + a*96 + c*12);
    op[0] = make_float4(od[0], od[1], od[2],  od[3]);
    op[1] = make_float4(od[4], od[5], od[6],  od[7]);
    op[2] = make_float4(od[8], od[9], od[10], od[11]);
}

extern "C" void kernel_launch(void* const* d_in, const int* in_sizes, int n_in,
                              void* d_out, int out_size, void* d_ws, size_t ws_size,
                              hipStream_t stream) {
    const float* x   = (const float*)d_in[0];
    const float* wq1 = (const float*)d_in[1];
    const float* wq2 = (const float*)d_in[2];
    const float* wq3 = (const float*)d_in[3];
    const float* bq  = (const float*)d_in[4];
    const float* wk1 = (const float*)d_in[5];
    const float* wk2 = (const float*)d_in[6];
    const float* wk3 = (const float*)d_in[7];
    const float* bk  = (const float*)d_in[8];
    const float* wv1 = (const float*)d_in[9];
    const float* wv2 = (const float*)d_in[10];
    const float* wv3 = (const float*)d_in[11];
    const float* bv  = (const float*)d_in[12];
    const float* wo1 = (const float*)d_in[13];
    const float* wo2 = (const float*)d_in[14];
    const float* wo3 = (const float*)d_in[15];
    const float* bo  = (const float*)d_in[16];
    float* out = (float*)d_out;

    char* ws = (char*)d_ws;
    const size_t SZ_Q  = (size_t)512 * SP * QW * 2;            // 31.5 MB
    const size_t SZ_K  = (size_t)512 * SP * DP * 2;            // 41.9 MB
    __hip_bfloat16* Qb = (__hip_bfloat16*)ws;
    __hip_bfloat16* Kb = (__hip_bfloat16*)(ws + SZ_Q);
    __hip_bfloat16* Vr = (__hip_bfloat16*)(ws + SZ_Q + SZ_K);
    __hip_bfloat16* Vt = (__hip_bfloat16*)(ws + SZ_Q + 2*SZ_K);   // [512][64][640]
    __hip_bfloat16* Ob = (__hip_bfloat16*)(ws + SZ_Q + 3*SZ_K);   // [32][600][768] bf16

    tle_qkv<<<Bc*Sc/16, 256, 0, stream>>>(x, wq1, wq2, wq3, bq,
                                          wk1, wk2, wk3, bk,
                                          wv1, wv2, wv3, bv, Qb, Kb, Vr);
    vtrans<<<dim3(512, 10), 256, 0, stream>>>(Vr, Vt, Kb);
    attn_mfma<<<2560, 64, 0, stream>>>(Qb, Kb, Vt, Ob);
    tle_out<<<Bc*Sc/4, 256, 0, stream>>>(Ob, wo1, wo2, wo3, bo, out);
}